// Round 20
// baseline (373.329 us; speedup 1.0000x reference)
//
#include <hip/hip_runtime.h>
#include <hip/hip_bf16.h>
#include <math.h>

typedef __bf16 bf16_t;
typedef __bf16 bf16x8 __attribute__((ext_vector_type(8)));
typedef __bf16 bf16x4 __attribute__((ext_vector_type(4)));
typedef float f32x4 __attribute__((ext_vector_type(4)));
typedef float f32x16 __attribute__((ext_vector_type(16)));
typedef unsigned int u32;

#define MFMA16 __builtin_amdgcn_mfma_f32_16x16x32_bf16
#define MFMA32 __builtin_amdgcn_mfma_f32_32x32x16_bf16

static __device__ __forceinline__ u32 pkbf(float a, float b) {
  union { bf16_t h[2]; u32 u; } z;
  z.h[0] = (bf16_t)a; z.h[1] = (bf16_t)b;
  return z.u;
}

// async global->LDS, 16B per lane, dest = wave-uniform base + lane*16
static __device__ __forceinline__ void gload16(const bf16_t* g, bf16_t* l) {
  __builtin_amdgcn_global_load_lds(
      (const __attribute__((address_space(1))) void*)g,
      (__attribute__((address_space(3))) void*)l, 16, 0, 0);
}

// ------- merged prep: x->bf16 | weight transposes | sincos table -----------
__global__ void k_prep(const float* __restrict__ x,
                       const float* __restrict__ Wq, const float* __restrict__ Wk,
                       const float* __restrict__ Wv, const float* __restrict__ Wp,
                       bf16_t* __restrict__ xb, bf16_t* __restrict__ WqkvT,
                       bf16_t* __restrict__ WpT, float2* __restrict__ tab) {
  int bx = blockIdx.x;
  if (bx >= 168) {  // x conversion
    long base = (((long)(bx - 168) * 64 + blockIdx.y) * 256 + threadIdx.x) * 8L;
    const float4 v0 = *(const float4*)(x + base);
    const float4 v1 = *(const float4*)(x + base + 4);
    bf16x8 o;
    o[0] = (bf16_t)v0.x; o[1] = (bf16_t)v0.y; o[2] = (bf16_t)v0.z; o[3] = (bf16_t)v0.w;
    o[4] = (bf16_t)v1.x; o[5] = (bf16_t)v1.y; o[6] = (bf16_t)v1.z; o[7] = (bf16_t)v1.w;
    *(bf16x8*)(xb + base) = o;
    return;
  }
  if (bx >= 160) {  // sincos
    int idx = ((bx - 160) * 64 + blockIdx.y) * 256 + threadIdx.x;
    int t = idx >> 6, i = idx & 63;
    float theta = exp2f(-(float)i * 0.41524101186092029f);
    float s, c;
    sincosf((float)t * theta, &s, &c);
    tab[idx] = make_float2(c, s);
    return;
  }
  __shared__ float tile[32][33];
  int k0 = blockIdx.y * 32;
  const float* W;
  bf16_t* WT;
  int n0, N;
  if (bx < 64)      { W = Wq; WT = WqkvT;                       n0 = bx * 32;        N = 2048; }
  else if (bx < 80) { W = Wk; WT = WqkvT + (size_t)2048 * 2048; n0 = (bx - 64) * 32; N = 512; }
  else if (bx < 96) { W = Wv; WT = WqkvT + (size_t)2560 * 2048; n0 = (bx - 80) * 32; N = 512; }
  else              { W = Wp; WT = WpT;                         n0 = (bx - 96) * 32; N = 2048; }
  int tx = threadIdx.x & 31, ty = threadIdx.x >> 5;
#pragma unroll
  for (int i = 0; i < 4; i++)
    tile[ty + i * 8][tx] = W[(size_t)(k0 + ty + i * 8) * N + n0 + tx];
  __syncthreads();
#pragma unroll
  for (int i = 0; i < 4; i++) {
    int n = ty + i * 8;
    WT[(size_t)(n0 + n) * 2048 + k0 + tx] = (bf16_t)tile[tx][n];
  }
}

// ---------------- GEMM v4: 256x256 tile, 8-wave, 4-phase/K-tile pipeline ----
template <bool QKV>
__global__ __launch_bounds__(512, 2) void k_gemm_bt(
    const bf16_t* __restrict__ A, const bf16_t* __restrict__ BT,
    bf16_t* __restrict__ Cqk, bf16_t* __restrict__ VTout, float* __restrict__ Cf,
    const float* __restrict__ bias, const float2* __restrict__ tab,
    int M, int N, int K, int nwg) {
  __shared__ bf16_t smem[65536];
  const int nbn = N >> 8;
  int orig = (int)blockIdx.x;
  int swz = (orig & 7) * (nwg >> 3) + (orig >> 3);
  int bm = swz / nbn, bn = swz % nbn;
  const int tid = threadIdx.x;
  const int lane = tid & 63, wid = tid >> 6;
  const int wm = (wid >> 2) << 7;
  const int wn = (wid & 3) << 6;
  const int lr = lane & 15, lq = lane >> 4;
  f32x4 acc[8][4] = {};

  const int rl = tid >> 3;
  const int ss = (tid & 7) ^ (rl & 7);
  const bf16_t* gA = A + (size_t)(bm * 256 + rl) * K + ss * 8;
  const bf16_t* gB = BT + (size_t)(bn * 256 + rl) * K + ss * 8;
  const int lo = wid * 512;

  const int nt = K >> 6;
  {
    bf16_t* sA0 = smem;
    bf16_t* sB0 = smem + 16384;
#pragma unroll
    for (int i = 0; i < 4; i++) {
      gload16(gA + (size_t)i * 64 * K, sA0 + i * 4096 + lo);
      gload16(gB + (size_t)i * 64 * K, sB0 + i * 4096 + lo);
    }
  }
  asm volatile("s_waitcnt vmcnt(0)" ::: "memory");
  __syncthreads();

  for (int t = 0; t < nt; ++t) {
    bf16_t* sAc = smem + (t & 1) * 32768;
    bf16_t* sBc = sAc + 16384;
    bf16_t* sAn = smem + ((t & 1) ^ 1) * 32768;
    bf16_t* sBn = sAn + 16384;
    const int k1 = (t + 1) << 6;
    bf16x8 breg[4][2];
#pragma unroll
    for (int n = 0; n < 4; n++)
#pragma unroll
      for (int kk = 0; kk < 2; kk++) {
        int R = wn + n * 16 + lr;
        int u = (kk * 4 + lq) ^ (R & 7);
        breg[n][kk] = *(const bf16x8*)&sBc[R * 64 + u * 8];
      }
    {
      bf16x8 areg[2][2];
#pragma unroll
      for (int ml = 0; ml < 2; ml++)
#pragma unroll
        for (int kk = 0; kk < 2; kk++) {
          int R = wm + ml * 16 + lr;
          int u = (kk * 4 + lq) ^ (R & 7);
          areg[ml][kk] = *(const bf16x8*)&sAc[R * 64 + u * 8];
        }
      if (t + 1 < nt) {
#pragma unroll
        for (int i = 0; i < 4; i++) {
          gload16(gA + (size_t)i * 64 * K + k1, sAn + i * 4096 + lo);
          gload16(gB + (size_t)i * 64 * K + k1, sBn + i * 4096 + lo);
        }
      }
      __builtin_amdgcn_s_barrier();
      asm volatile("s_waitcnt lgkmcnt(0)" ::: "memory");
      __builtin_amdgcn_sched_barrier(0);
      __builtin_amdgcn_s_setprio(1);
#pragma unroll
      for (int ml = 0; ml < 2; ml++)
#pragma unroll
        for (int n = 0; n < 4; n++)
#pragma unroll
          for (int kk = 0; kk < 2; kk++)
            acc[ml][n] = MFMA16(areg[ml][kk], breg[n][kk], acc[ml][n], 0, 0, 0);
      __builtin_amdgcn_s_setprio(0);
      __builtin_amdgcn_s_barrier();
    }
#pragma unroll
    for (int p = 1; p < 4; p++) {
      bf16x8 areg[2][2];
#pragma unroll
      for (int ml = 0; ml < 2; ml++)
#pragma unroll
        for (int kk = 0; kk < 2; kk++) {
          int R = wm + (2 * p + ml) * 16 + lr;
          int u = (kk * 4 + lq) ^ (R & 7);
          areg[ml][kk] = *(const bf16x8*)&sAc[R * 64 + u * 8];
        }
      __builtin_amdgcn_s_barrier();
      asm volatile("s_waitcnt lgkmcnt(0)" ::: "memory");
      __builtin_amdgcn_sched_barrier(0);
      __builtin_amdgcn_s_setprio(1);
#pragma unroll
      for (int ml = 0; ml < 2; ml++)
#pragma unroll
        for (int n = 0; n < 4; n++)
#pragma unroll
          for (int kk = 0; kk < 2; kk++)
            acc[2 * p + ml][n] = MFMA16(areg[ml][kk], breg[n][kk], acc[2 * p + ml][n], 0, 0, 0);
      __builtin_amdgcn_s_setprio(0);
      if (p == 3) {
        asm volatile("s_waitcnt vmcnt(0)" ::: "memory");
        __builtin_amdgcn_sched_barrier(0);
      }
      __builtin_amdgcn_s_barrier();
    }
  }
  // ---- epilogue ----
  if constexpr (QKV) {
    if (bn < 10) {  // q,k -> RoPE in-register -> qkv2 [M][2560]
#pragma unroll
      for (int m = 0; m < 8; m++) {
        int row0 = bm * 256 + wm + m * 16 + lq * 4;
#pragma unroll
        for (int n = 0; n < 4; n++) {
          int col = bn * 256 + wn + n * 16 + lr;
          int i = (col >> 1) & 63;
          bool odd = (col & 1) != 0;
#pragma unroll
          for (int r = 0; r < 4; r++) {
            float mine = acc[m][n][r];
            float other = __shfl_xor(mine, 1);
            int tt = (row0 + r) & 2047;
            float2 cs = tab[tt * 64 + i];
            float e = odd ? other : mine;
            float o = odd ? mine : other;
            float res = odd ? fmaf(e, cs.y, o * cs.x) : fmaf(e, cs.x, -o * cs.y);
            Cqk[(size_t)(row0 + r) * 2560 + col] = (bf16_t)res;
          }
        }
      }
    } else {  // v -> VT
#pragma unroll
      for (int m = 0; m < 8; m++) {
        int row0 = bm * 256 + wm + m * 16 + lq * 4;
        int b = row0 >> 11;
        int t0 = row0 - (b << 11);
#pragma unroll
        for (int n = 0; n < 4; n++) {
          int colp = bn * 256 + wn + n * 16 + lr - 2560 + b * 512;
          bf16x4 st;
#pragma unroll
          for (int r = 0; r < 4; r++) st[r] = (bf16_t)acc[m][n][r];
          *(bf16x4*)&VTout[(size_t)colp * 2048 + t0] = st;
        }
      }
    }
  } else {
#pragma unroll
    for (int m = 0; m < 8; m++) {
      int row0 = bm * 256 + wm + m * 16 + lq * 4;
#pragma unroll
      for (int n = 0; n < 4; n++) {
        int col = bn * 256 + wn + n * 16 + lr;
#pragma unroll
        for (int r = 0; r < 4; r++)
          Cf[(size_t)(row0 + r) * N + col] = acc[m][n][r] + bias[col];
      }
    }
  }
}

// ---------------- Flash attention v15 (causal, GQA) — T15 cross-tile pipeline
// Iter kt: barrier -> publish V(kt) -> prefetch(kt+1) -> QK(kt) -> finish(kt-1)
// (softmax+PV of prev tile overlaps QK MFMAs; one barrier/tile; prev V lives
// in sVT[cur^1], untouched by this iter's writes -> race-free).
__global__ __launch_bounds__(256, 2) void k_attn(const bf16_t* __restrict__ qkv2,
                                                 const bf16_t* __restrict__ VT,
                                                 bf16_t* __restrict__ out) {
  __shared__ bf16_t sK[2][64 * 128];   // [k][d granule^row]; dbuf (gload_lds)
  __shared__ bf16_t sVT[2][128 * 72];  // [d][k] + 8 pad, dbuf
  int bid = blockIdx.x;
  int g = bid >> 6;
  int qt = (g & 1) ? (g >> 1) : (15 - (g >> 1));
  int bh = bid & 63;
  int h = bh & 15, b = bh >> 4;
  int kvh = h >> 2;
  const size_t RS = 2560;
  const bf16_t* Qb = qkv2 + (size_t)b * 2048 * RS + h * 128;
  const bf16_t* Kb = qkv2 + (size_t)b * 2048 * RS + 2048 + kvh * 128;
  const bf16_t* Vt = VT + (size_t)(b * 4 + kvh) * 128 * 2048;
  int q0 = qt * 128;
  int tid = threadIdx.x, lane = tid & 63, wid = tid >> 6;
  int l31 = lane & 31, hi = lane >> 5;
  int qw = q0 + wid * 32;

  bf16x8 qf[8];
  {
    const bf16_t* qrow = Qb + (size_t)(qw + l31) * RS + hi * 8;
#pragma unroll
    for (int dc = 0; dc < 8; dc++)
      qf[dc] = *(const bf16x8*)(qrow + dc * 16);
  }

  const int rlk = tid >> 4;
  const bf16_t* Kst = Kb + (size_t)rlk * RS + (size_t)(((tid & 15) ^ (rlk & 7)) * 8);
  const int lo = wid * 512;
  int vd = tid >> 3, vk = (tid & 7) * 8;

  f32x16 oT[4] = {};
  float m_r = -INFINITY, l_r = 0.f;
  const float SC = 0.08838834764831845f * 1.4426950408889634f;

  bf16x8 vreg[4];
  auto issueV = [&](int k0) {
#pragma unroll
    for (int ps = 0; ps < 4; ps++)
      vreg[ps] = *(const bf16x8*)(Vt + (size_t)(vd + ps * 32) * 2048 + k0 + vk);
  };
  auto issueK = [&](int k0, int buf) {
#pragma unroll
    for (int i = 0; i < 4; i++)
      gload16(Kst + (size_t)(k0 + i * 16) * RS, &sK[buf][i * 2048 + lo]);
  };

  // finish(prev tile): softmax + pack + PV. kp0 = prev k-base, sVc = prev V.
  f32x16 pvA = {}, pvB = {};  // carried prev-tile raw scores (T15 state)
  auto finish = [&](int kp0, const bf16_t* sVc) {
    float p[2][16];
    int qg = qw + l31;
    if (kp0 + 63 <= qw) {
#pragma unroll
      for (int r = 0; r < 16; r++) { p[0][r] = pvA[r]; p[1][r] = pvB[r]; }
    } else {
#pragma unroll
      for (int nf = 0; nf < 2; nf++)
#pragma unroll
        for (int r = 0; r < 16; r++) {
          int kg = kp0 + nf * 32 + (r & 3) + 8 * (r >> 2) + 4 * hi;
          p[nf][r] = (kg <= qg) ? (nf ? pvB[r] : pvA[r]) : -INFINITY;
        }
    }
    float mx[16];
#pragma unroll
    for (int r = 0; r < 16; r++) mx[r] = fmaxf(p[0][r], p[1][r]);
#pragma unroll
    for (int s = 8; s >= 1; s >>= 1)
#pragma unroll
      for (int r = 0; r < 8; r++)
        if (r < s) mx[r] = fmaxf(mx[r], mx[r + s]);
    float pm = mx[0] * SC;
    pm = fmaxf(pm, __shfl_xor(pm, 32));
    bool skip = __all(pm <= m_r + 8.f);
    float mn = skip ? m_r : fmaxf(m_r, pm);
    float alpha = skip ? 1.f : exp2f(m_r - mn);
    m_r = mn;
    float nm = -m_r;
#pragma unroll
    for (int nf = 0; nf < 2; nf++)
#pragma unroll
      for (int r = 0; r < 16; r++)
        p[nf][r] = exp2f(fmaf(p[nf][r], SC, nm));
    float sm[16];
#pragma unroll
    for (int r = 0; r < 16; r++) sm[r] = p[0][r] + p[1][r];
#pragma unroll
    for (int s = 8; s >= 1; s >>= 1)
#pragma unroll
      for (int r = 0; r < 8; r++)
        if (r < s) sm[r] += sm[r + s];
    float rs = sm[0] + __shfl_xor(sm[0], 32);
    l_r = l_r * alpha + rs;
    if (!skip) {
#pragma unroll
      for (int c = 0; c < 4; c++)
#pragma unroll
        for (int r = 0; r < 16; r++) oT[c][r] *= alpha;
    }
#pragma unroll
    for (int nf = 0; nf < 2; nf++) {
      u32 Qk[4][2];
#pragma unroll
      for (int gg = 0; gg < 4; gg++) {
        Qk[gg][0] = pkbf(p[nf][4 * gg + 0], p[nf][4 * gg + 1]);
        Qk[gg][1] = pkbf(p[nf][4 * gg + 2], p[nf][4 * gg + 3]);
      }
#pragma unroll
      for (int kc = 0; kc < 2; kc++) {
        u32 x0 = __shfl_xor(Qk[2 * kc + 1 - hi][0], 32);
        u32 x1 = __shfl_xor(Qk[2 * kc + 1 - hi][1], 32);
        u32 o0 = Qk[2 * kc + hi][0], o1 = Qk[2 * kc + hi][1];
        union { u32 w[4]; bf16x8 v; } pf;
        pf.w[0] = hi ? x0 : o0;
        pf.w[1] = hi ? x1 : o1;
        pf.w[2] = hi ? o0 : x0;
        pf.w[3] = hi ? o1 : x1;
        int slot = nf * 2 + kc;
        __builtin_amdgcn_s_setprio(1);
#pragma unroll
        for (int c = 0; c < 4; c++) {
          bf16x8 vf = *(const bf16x8*)&sVc[(c * 32 + l31) * 72 + slot * 16 + hi * 8];
          oT[c] = MFMA32(vf, pf.v, oT[c], 0, 0, 0);
        }
        __builtin_amdgcn_s_setprio(0);
      }
    }
  };

  int ntiles = 2 * qt + 2;
  issueK(0, 0);
  issueV(0);
  for (int kt = 0; kt < ntiles; kt++) {
    int k0 = kt * 64;
    int cur = kt & 1;
    __syncthreads();  // drains vmcnt (K gloads + V regs of tile kt); all waves
                      // done with PV(kt-2) reads of sVT[cur] -> safe to write
#pragma unroll
    for (int ps = 0; ps < 4; ps++)
      *(bf16x8*)&sVT[cur][(vd + ps * 32) * 72 + vk] = vreg[ps];
    if (kt + 1 < ntiles) {
      issueK(k0 + 64, cur ^ 1);
      issueV(k0 + 64);
    }
    bool liveCur = (k0 <= qw + 31);  // wave-uniform
    f32x16 sa0 = {}, sa1 = {};
    if (liveCur) {
      const char* sKc = (const char*)sK[cur];
      __builtin_amdgcn_s_setprio(1);
#pragma unroll
      for (int dc = 0; dc < 8; dc++) {
        int cb = (dc * 32 + hi * 16) ^ ((l31 & 7) << 4);
        bf16x8 kf0 = *(const bf16x8*)(sKc + l31 * 256 + cb);
        bf16x8 kf1 = *(const bf16x8*)(sKc + (32 + l31) * 256 + cb);
        sa0 = MFMA32(kf0, qf[dc], sa0, 0, 0, 0);
        sa1 = MFMA32(kf1, qf[dc], sa1, 0, 0, 0);
      }
      __builtin_amdgcn_s_setprio(0);
    }
    // finish prev tile (independent VALU chain; overlaps the QK MFMAs above)
    if (kt >= 1 && (k0 - 64) <= qw + 31)
      finish(k0 - 64, sVT[cur ^ 1]);
    if (liveCur) { pvA = sa0; pvB = sa1; }
  }
  __syncthreads();  // publish last tile's sVT writes to all waves
  if ((ntiles - 1) * 64 <= qw + 31)
    finish((ntiles - 1) * 64, sVT[(ntiles - 1) & 1]);

  // --- epilogue: O^T store, lane-local l ---
  float inv = 1.f / l_r;
  size_t row = (size_t)b * 2048 + qw + l31;
#pragma unroll
  for (int c = 0; c < 4; c++)
#pragma unroll
    for (int rr = 0; rr < 4; rr++) {
      bf16x4 o4;
#pragma unroll
      for (int j = 0; j < 4; j++) o4[j] = (bf16_t)(oT[c][rr * 4 + j] * inv);
      *(bf16x4*)(out + row * 2048 + h * 128 + c * 32 + rr * 8 + hi * 4) = o4;
    }
}

extern "C" void kernel_launch(void* const* d_in, const int* in_sizes, int n_in,
                              void* d_out, int out_size, void* d_ws, size_t ws_size,
                              hipStream_t stream) {
  const float* x = (const float*)d_in[0];
  const float* Wq = (const float*)d_in[1];
  const float* Wk = (const float*)d_in[2];
  const float* Wv = (const float*)d_in[3];
  const float* Wp = (const float*)d_in[4];
  const float* bp = (const float*)d_in[5];
  float* out = (float*)d_out;

  bf16_t* ws = (bf16_t*)d_ws;
  bf16_t* xb = ws;                            // 16.78M  (attn out aliases this)
  bf16_t* qkv2 = ws + 16777216;               // 8192x2560 (q,k only)
  bf16_t* VT = qkv2 + 20971520;               // 2048x2048 (V transposed)
  bf16_t* WqkvT = VT + 4194304;               // 3072x2048
  bf16_t* WpT = WqkvT + 6291456;              // 2048x2048
  float2* tab = (float2*)(WpT + 4194304);     // 1MB table after WpT

  k_prep<<<dim3(296, 64), 256, 0, stream>>>(x, Wq, Wk, Wv, Wp, xb, WqkvT, WpT, tab);

  k_gemm_bt<true><<<384, 512, 0, stream>>>(xb, WqkvT, qkv2, VT, nullptr, nullptr, tab, 8192, 3072, 2048, 384);
  k_attn<<<1024, 256, 0, stream>>>(qkv2, VT, xb);
  k_gemm_bt<false><<<256, 512, 0, stream>>>(xb, WpT, nullptr, nullptr, out, bp, nullptr, 8192, 2048, 2048, 256);
}

// Round 21
// 369.498 us; speedup vs baseline: 1.0104x; 1.0104x over previous
//
#include <hip/hip_runtime.h>
#include <hip/hip_bf16.h>
#include <math.h>

typedef __bf16 bf16_t;
typedef __bf16 bf16x8 __attribute__((ext_vector_type(8)));
typedef __bf16 bf16x4 __attribute__((ext_vector_type(4)));
typedef float f32x4 __attribute__((ext_vector_type(4)));
typedef float f32x16 __attribute__((ext_vector_type(16)));
typedef unsigned int u32;

#define MFMA16 __builtin_amdgcn_mfma_f32_16x16x32_bf16
#define MFMA32 __builtin_amdgcn_mfma_f32_32x32x16_bf16

static __device__ __forceinline__ u32 pkbf(float a, float b) {
  union { bf16_t h[2]; u32 u; } z;
  z.h[0] = (bf16_t)a; z.h[1] = (bf16_t)b;
  return z.u;
}

// async global->LDS, 16B per lane, dest = wave-uniform base + lane*16
static __device__ __forceinline__ void gload16(const bf16_t* g, bf16_t* l) {
  __builtin_amdgcn_global_load_lds(
      (const __attribute__((address_space(1))) void*)g,
      (__attribute__((address_space(3))) void*)l, 16, 0, 0);
}

// ------- merged prep: x->bf16 | weight transposes | sincos table -----------
// bx: [0,64) Wq, [64,80) Wk, [80,96) Wv, [96,160) Wp, [160,168) sincos,
//     [168,296) x conversion (128 x 64 blocks x 256 thr x 8 elems = 16.78M).
__global__ void k_prep(const float* __restrict__ x,
                       const float* __restrict__ Wq, const float* __restrict__ Wk,
                       const float* __restrict__ Wv, const float* __restrict__ Wp,
                       bf16_t* __restrict__ xb, bf16_t* __restrict__ WqkvT,
                       bf16_t* __restrict__ WpT, float2* __restrict__ tab) {
  int bx = blockIdx.x;
  if (bx >= 168) {  // x conversion
    long base = (((long)(bx - 168) * 64 + blockIdx.y) * 256 + threadIdx.x) * 8L;
    const float4 v0 = *(const float4*)(x + base);
    const float4 v1 = *(const float4*)(x + base + 4);
    bf16x8 o;
    o[0] = (bf16_t)v0.x; o[1] = (bf16_t)v0.y; o[2] = (bf16_t)v0.z; o[3] = (bf16_t)v0.w;
    o[4] = (bf16_t)v1.x; o[5] = (bf16_t)v1.y; o[6] = (bf16_t)v1.z; o[7] = (bf16_t)v1.w;
    *(bf16x8*)(xb + base) = o;
    return;
  }
  if (bx >= 160) {  // sincos: 8 x 64 blocks x 256 thr = 131072 = 2048*64
    int idx = ((bx - 160) * 64 + blockIdx.y) * 256 + threadIdx.x;
    int t = idx >> 6, i = idx & 63;
    float theta = exp2f(-(float)i * 0.41524101186092029f);  // 10000^(-i/32)
    float s, c;
    sincosf((float)t * theta, &s, &c);
    tab[idx] = make_float2(c, s);
    return;
  }
  __shared__ float tile[32][33];
  int k0 = blockIdx.y * 32;
  const float* W;
  bf16_t* WT;
  int n0, N;
  if (bx < 64)      { W = Wq; WT = WqkvT;                       n0 = bx * 32;        N = 2048; }
  else if (bx < 80) { W = Wk; WT = WqkvT + (size_t)2048 * 2048; n0 = (bx - 64) * 32; N = 512; }
  else if (bx < 96) { W = Wv; WT = WqkvT + (size_t)2560 * 2048; n0 = (bx - 80) * 32; N = 512; }
  else              { W = Wp; WT = WpT;                         n0 = (bx - 96) * 32; N = 2048; }
  int tx = threadIdx.x & 31, ty = threadIdx.x >> 5;
#pragma unroll
  for (int i = 0; i < 4; i++)
    tile[ty + i * 8][tx] = W[(size_t)(k0 + ty + i * 8) * N + n0 + tx];
  __syncthreads();
#pragma unroll
  for (int i = 0; i < 4; i++) {
    int n = ty + i * 8;
    WT[(size_t)(n0 + n) * 2048 + k0 + tx] = (bf16_t)tile[tx][n];
  }
}

// ---------------- GEMM v4: 256x256 tile, 8-wave, 4-phase/K-tile pipeline ----
// QKV=true:  q,k cols (bn<10) -> RoPE applied in-register -> Cqk [M][2560];
//            v cols (bn>=10) -> VT[colp][t].
// QKV=false: f32 out + bias, row stride N.
template <bool QKV>
__global__ __launch_bounds__(512, 2) void k_gemm_bt(
    const bf16_t* __restrict__ A, const bf16_t* __restrict__ BT,
    bf16_t* __restrict__ Cqk, bf16_t* __restrict__ VTout, float* __restrict__ Cf,
    const float* __restrict__ bias, const float2* __restrict__ tab,
    int M, int N, int K, int nwg) {
  __shared__ bf16_t smem[65536];  // [2 buf][A 16384 | B 16384]
  const int nbn = N >> 8;
  int orig = (int)blockIdx.x;
  int swz = (orig & 7) * (nwg >> 3) + (orig >> 3);  // bijective, nwg%8==0
  int bm = swz / nbn, bn = swz % nbn;
  const int tid = threadIdx.x;
  const int lane = tid & 63, wid = tid >> 6;
  const int wm = (wid >> 2) << 7;  // 0 / 128
  const int wn = (wid & 3) << 6;   // 0 / 64 / 128 / 192
  const int lr = lane & 15, lq = lane >> 4;
  f32x4 acc[8][4] = {};

  const int rl = tid >> 3;               // row within 64-row chunk
  const int ss = (tid & 7) ^ (rl & 7);   // pre-swizzled source 16B-slot
  const bf16_t* gA = A + (size_t)(bm * 256 + rl) * K + ss * 8;
  const bf16_t* gB = BT + (size_t)(bn * 256 + rl) * K + ss * 8;
  const int lo = wid * 512;  // wave-uniform LDS offset within issue chunk

  const int nt = K >> 6;
  {  // prologue: stage tile 0, full drain once
    bf16_t* sA0 = smem;
    bf16_t* sB0 = smem + 16384;
#pragma unroll
    for (int i = 0; i < 4; i++) {
      gload16(gA + (size_t)i * 64 * K, sA0 + i * 4096 + lo);
      gload16(gB + (size_t)i * 64 * K, sB0 + i * 4096 + lo);
    }
  }
  asm volatile("s_waitcnt vmcnt(0)" ::: "memory");
  __syncthreads();

  for (int t = 0; t < nt; ++t) {
    bf16_t* sAc = smem + (t & 1) * 32768;
    bf16_t* sBc = sAc + 16384;
    bf16_t* sAn = smem + ((t & 1) ^ 1) * 32768;
    bf16_t* sBn = sAn + 16384;
    const int k1 = (t + 1) << 6;
    bf16x8 breg[4][2];
    // ---- phase 0: read all B frags + A frags m0,m1; issue next tile ----
#pragma unroll
    for (int n = 0; n < 4; n++)
#pragma unroll
      for (int kk = 0; kk < 2; kk++) {
        int R = wn + n * 16 + lr;
        int u = (kk * 4 + lq) ^ (R & 7);
        breg[n][kk] = *(const bf16x8*)&sBc[R * 64 + u * 8];
      }
    {
      bf16x8 areg[2][2];
#pragma unroll
      for (int ml = 0; ml < 2; ml++)
#pragma unroll
        for (int kk = 0; kk < 2; kk++) {
          int R = wm + ml * 16 + lr;
          int u = (kk * 4 + lq) ^ (R & 7);
          areg[ml][kk] = *(const bf16x8*)&sAc[R * 64 + u * 8];
        }
      if (t + 1 < nt) {
#pragma unroll
        for (int i = 0; i < 4; i++) {
          gload16(gA + (size_t)i * 64 * K + k1, sAn + i * 4096 + lo);
          gload16(gB + (size_t)i * 64 * K + k1, sBn + i * 4096 + lo);
        }
      }
      __builtin_amdgcn_s_barrier();
      asm volatile("s_waitcnt lgkmcnt(0)" ::: "memory");
      __builtin_amdgcn_sched_barrier(0);
      __builtin_amdgcn_s_setprio(1);
#pragma unroll
      for (int ml = 0; ml < 2; ml++)
#pragma unroll
        for (int n = 0; n < 4; n++)
#pragma unroll
          for (int kk = 0; kk < 2; kk++)
            acc[ml][n] = MFMA16(areg[ml][kk], breg[n][kk], acc[ml][n], 0, 0, 0);
      __builtin_amdgcn_s_setprio(0);
      __builtin_amdgcn_s_barrier();
    }
    // ---- phases 1..3: A frags m=2p..2p+1 ----
#pragma unroll
    for (int p = 1; p < 4; p++) {
      bf16x8 areg[2][2];
#pragma unroll
      for (int ml = 0; ml < 2; ml++)
#pragma unroll
        for (int kk = 0; kk < 2; kk++) {
          int R = wm + (2 * p + ml) * 16 + lr;
          int u = (kk * 4 + lq) ^ (R & 7);
          areg[ml][kk] = *(const bf16x8*)&sAc[R * 64 + u * 8];
        }
      __builtin_amdgcn_s_barrier();
      asm volatile("s_waitcnt lgkmcnt(0)" ::: "memory");
      __builtin_amdgcn_sched_barrier(0);
      __builtin_amdgcn_s_setprio(1);
#pragma unroll
      for (int ml = 0; ml < 2; ml++)
#pragma unroll
        for (int n = 0; n < 4; n++)
#pragma unroll
          for (int kk = 0; kk < 2; kk++)
            acc[2 * p + ml][n] = MFMA16(areg[ml][kk], breg[n][kk], acc[2 * p + ml][n], 0, 0, 0);
      __builtin_amdgcn_s_setprio(0);
      if (p == 3) {
        asm volatile("s_waitcnt vmcnt(0)" ::: "memory");
        __builtin_amdgcn_sched_barrier(0);
      }
      __builtin_amdgcn_s_barrier();
    }
  }
  // ---- epilogue ----
  if constexpr (QKV) {
    if (bn < 10) {  // q,k -> RoPE in-register -> qkv2 [M][2560]
#pragma unroll
      for (int m = 0; m < 8; m++) {
        int row0 = bm * 256 + wm + m * 16 + lq * 4;
#pragma unroll
        for (int n = 0; n < 4; n++) {
          int col = bn * 256 + wn + n * 16 + lr;
          int i = (col >> 1) & 63;
          bool odd = (col & 1) != 0;
#pragma unroll
          for (int r = 0; r < 4; r++) {
            float mine = acc[m][n][r];
            float other = __shfl_xor(mine, 1);
            int tt = (row0 + r) & 2047;
            float2 cs = tab[tt * 64 + i];
            float e = odd ? other : mine;
            float o = odd ? mine : other;
            float res = odd ? fmaf(e, cs.y, o * cs.x) : fmaf(e, cs.x, -o * cs.y);
            Cqk[(size_t)(row0 + r) * 2560 + col] = (bf16_t)res;
          }
        }
      }
    } else {  // v -> VT[col-2560 + b*512][t], t = row - b*2048
#pragma unroll
      for (int m = 0; m < 8; m++) {
        int row0 = bm * 256 + wm + m * 16 + lq * 4;
        int b = row0 >> 11;
        int t0 = row0 - (b << 11);
#pragma unroll
        for (int n = 0; n < 4; n++) {
          int colp = bn * 256 + wn + n * 16 + lr - 2560 + b * 512;
          bf16x4 st;
#pragma unroll
          for (int r = 0; r < 4; r++) st[r] = (bf16_t)acc[m][n][r];
          *(bf16x4*)&VTout[(size_t)colp * 2048 + t0] = st;
        }
      }
    }
  } else {
#pragma unroll
    for (int m = 0; m < 8; m++) {
      int row0 = bm * 256 + wm + m * 16 + lq * 4;
#pragma unroll
      for (int n = 0; n < 4; n++) {
        int col = bn * 256 + wn + n * 16 + lr;
#pragma unroll
        for (int r = 0; r < 4; r++)
          Cf[(size_t)(row0 + r) * N + col] = acc[m][n][r] + bias[col];
      }
    }
  }
}

// ---------------- Flash attention v12 (causal, GQA) — round-16 best ---------
// Fused 64-wide softmax, K via global_load_lds dbuf, V reg-staged into
// double-buffered padded sVT, ONE barrier/tile, launch_bounds(256,2).
__global__ __launch_bounds__(256, 2) void k_attn(const bf16_t* __restrict__ qkv2,
                                                 const bf16_t* __restrict__ VT,
                                                 bf16_t* __restrict__ out) {
  __shared__ bf16_t sK[2][64 * 128];   // [k][d granule^row]; dbuf for gload_lds
  __shared__ bf16_t sVT[2][128 * 72];  // [d][k] + 8 pad, dbuf
  int bid = blockIdx.x;
  int g = bid >> 6;
  int qt = (g & 1) ? (g >> 1) : (15 - (g >> 1));  // heavy/light interleave
  int bh = bid & 63;
  int h = bh & 15, b = bh >> 4;
  int kvh = h >> 2;
  const size_t RS = 2560;
  const bf16_t* Qb = qkv2 + (size_t)b * 2048 * RS + h * 128;
  const bf16_t* Kb = qkv2 + (size_t)b * 2048 * RS + 2048 + kvh * 128;
  const bf16_t* Vt = VT + (size_t)(b * 4 + kvh) * 128 * 2048;
  int q0 = qt * 128;
  int tid = threadIdx.x, lane = tid & 63, wid = tid >> 6;
  int l31 = lane & 31, hi = lane >> 5;
  int qw = q0 + wid * 32;

  // Q fragments (B operand: row=l31, k = dc*16 + hi*8 + j)
  bf16x8 qf[8];
  {
    const bf16_t* qrow = Qb + (size_t)(qw + l31) * RS + hi * 8;
#pragma unroll
    for (int dc = 0; dc < 8; dc++)
      qf[dc] = *(const bf16x8*)(qrow + dc * 16);
  }

  // K staging source, pre-swizzled (rule 21): row rlk, granule (tid&15)^(rlk&7)
  const int rlk = tid >> 4;
  const bf16_t* Kst = Kb + (size_t)rlk * RS + (size_t)(((tid & 15) ^ (rlk & 7)) * 8);
  const int lo = wid * 512;  // wave-uniform elem offset within 2048-elem chunk
  // V staging (reg path, padded sVT)
  int vd = tid >> 3, vk = (tid & 7) * 8;

  f32x16 oT[4] = {};
  float m_r = -INFINITY, l_r = 0.f;
  const float SC = 0.08838834764831845f * 1.4426950408889634f;  // D^-0.5 * log2(e)

  bf16x8 vreg[4];
  auto issueV = [&](int k0) {
#pragma unroll
    for (int ps = 0; ps < 4; ps++)
      vreg[ps] = *(const bf16x8*)(Vt + (size_t)(vd + ps * 32) * 2048 + k0 + vk);
  };
  auto issueK = [&](int k0, int buf) {
#pragma unroll
    for (int i = 0; i < 4; i++)
      gload16(Kst + (size_t)(k0 + i * 16) * RS, &sK[buf][i * 2048 + lo]);
  };

  int ntiles = 2 * qt + 2;
  issueK(0, 0);
  issueV(0);
  for (int kt = 0; kt < ntiles; kt++) {
    int k0 = kt * 64;
    int cur = kt & 1;
    // write V regs to sVT[cur]; implicit vmcnt wait on vreg also drains K gloads
#pragma unroll
    for (int ps = 0; ps < 4; ps++)
      *(bf16x8*)&sVT[cur][(vd + ps * 32) * 72 + vk] = vreg[ps];
    __syncthreads();  // ONE barrier/tile: sVT[cur] + sK[cur] published
    if (kt + 1 < ntiles) {
      issueK(k0 + 64, cur ^ 1);  // writes target the other buffers
      issueV(k0 + 64);
    }

    if (k0 <= qw + 31) {  // wave-uniform causal guard
      const char* sKc = (const char*)sK[cur];
      const bf16_t* sVc = sVT[cur];
      // --- S^T = K.Q^T : D[k][q], k=(r&3)+8*(r>>2)+4*hi (+32*nf), q=l31 ---
      f32x16 sa0 = {}, sa1 = {};
      __builtin_amdgcn_s_setprio(1);
#pragma unroll
      for (int dc = 0; dc < 8; dc++) {
        int cb = (dc * 32 + hi * 16) ^ ((l31 & 7) << 4);
        bf16x8 kf0 = *(const bf16x8*)(sKc + l31 * 256 + cb);
        bf16x8 kf1 = *(const bf16x8*)(sKc + (32 + l31) * 256 + cb);
        sa0 = MFMA32(kf0, qf[dc], sa0, 0, 0, 0);
        sa1 = MFMA32(kf1, qf[dc], sa1, 0, 0, 0);
      }
      __builtin_amdgcn_s_setprio(0);
      // --- raw-domain scores; mask only on diagonal tiles ---
      float p[2][16];
      int qg = qw + l31;
      if (k0 + 63 <= qw) {  // clean tile
#pragma unroll
        for (int r = 0; r < 16; r++) { p[0][r] = sa0[r]; p[1][r] = sa1[r]; }
      } else {              // diagonal tile
#pragma unroll
        for (int nf = 0; nf < 2; nf++)
#pragma unroll
          for (int r = 0; r < 16; r++) {
            int kg = k0 + nf * 32 + (r & 3) + 8 * (r >> 2) + 4 * hi;
            p[nf][r] = (kg <= qg) ? (nf ? sa1[r] : sa0[r]) : -INFINITY;
          }
      }
      // --- tree max (raw domain), scale once ---
      float mx[16];
#pragma unroll
      for (int r = 0; r < 16; r++) mx[r] = fmaxf(p[0][r], p[1][r]);
#pragma unroll
      for (int s = 8; s >= 1; s >>= 1)
#pragma unroll
        for (int r = 0; r < 8; r++)
          if (r < s) mx[r] = fmaxf(mx[r], mx[r + s]);
      float pm = mx[0] * SC;
      pm = fmaxf(pm, __shfl_xor(pm, 32));
      bool skip = __all(pm <= m_r + 8.f);  // defer-max (T13)
      float mn = skip ? m_r : fmaxf(m_r, pm);
      float alpha = skip ? 1.f : exp2f(m_r - mn);
      m_r = mn;
      float nm = -m_r;
      // --- exp via fma (SC folded) + tree sum ---
#pragma unroll
      for (int nf = 0; nf < 2; nf++)
#pragma unroll
        for (int r = 0; r < 16; r++)
          p[nf][r] = exp2f(fmaf(p[nf][r], SC, nm));
      float sm[16];
#pragma unroll
      for (int r = 0; r < 16; r++) sm[r] = p[0][r] + p[1][r];
#pragma unroll
      for (int s = 8; s >= 1; s >>= 1)
#pragma unroll
        for (int r = 0; r < 8; r++)
          if (r < s) sm[r] += sm[r + s];
      float rs = sm[0] + __shfl_xor(sm[0], 32);
      l_r = l_r * alpha + rs;
      if (!skip) {
#pragma unroll
        for (int c = 0; c < 4; c++)
#pragma unroll
          for (int r = 0; r < 16; r++) oT[c][r] *= alpha;
      }
      // --- P handoff in-register (pack + shfl_xor(32)) + PV: O^T += V^T P^T ---
#pragma unroll
      for (int nf = 0; nf < 2; nf++) {
        u32 Qk[4][2];
#pragma unroll
        for (int gg = 0; gg < 4; gg++) {
          Qk[gg][0] = pkbf(p[nf][4 * gg + 0], p[nf][4 * gg + 1]);
          Qk[gg][1] = pkbf(p[nf][4 * gg + 2], p[nf][4 * gg + 3]);
        }
#pragma unroll
        for (int kc = 0; kc < 2; kc++) {
          u32 x0 = __shfl_xor(Qk[2 * kc + 1 - hi][0], 32);
          u32 x1 = __shfl_xor(Qk[2 * kc + 1 - hi][1], 32);
          u32 o0 = Qk[2 * kc + hi][0], o1 = Qk[2 * kc + hi][1];
          union { u32 w[4]; bf16x8 v; } pf;
          pf.w[0] = hi ? x0 : o0;
          pf.w[1] = hi ? x1 : o1;
          pf.w[2] = hi ? o0 : x0;
          pf.w[3] = hi ? o1 : x1;
          int slot = nf * 2 + kc;
          __builtin_amdgcn_s_setprio(1);
#pragma unroll
          for (int c = 0; c < 4; c++) {
            bf16x8 vf = *(const bf16x8*)&sVc[(c * 32 + l31) * 72 + slot * 16 + hi * 8];
            oT[c] = MFMA32(vf, pf.v, oT[c], 0, 0, 0);
          }
          __builtin_amdgcn_s_setprio(0);
        }
      }
    }
    // no barrier2: next tile's LDS writes target the other buffers
  }
  // --- epilogue: O^T store, lane-local l ---
  float inv = 1.f / l_r;
  size_t row = (size_t)b * 2048 + qw + l31;
#pragma unroll
  for (int c = 0; c < 4; c++)
#pragma unroll
    for (int rr = 0; rr < 4; rr++) {
      bf16x4 o4;
#pragma unroll
      for (int j = 0; j < 4; j++) o4[j] = (bf16_t)(oT[c][rr * 4 + j] * inv);
      *(bf16x4*)(out + row * 2048 + h * 128 + c * 32 + rr * 8 + hi * 4) = o4;
    }
}

extern "C" void kernel_launch(void* const* d_in, const int* in_sizes, int n_in,
                              void* d_out, int out_size, void* d_ws, size_t ws_size,
                              hipStream_t stream) {
  const float* x = (const float*)d_in[0];
  const float* Wq = (const float*)d_in[1];
  const float* Wk = (const float*)d_in[2];
  const float* Wv = (const float*)d_in[3];
  const float* Wp = (const float*)d_in[4];
  const float* bp = (const float*)d_in[5];
  float* out = (float*)d_out;

  bf16_t* ws = (bf16_t*)d_ws;
  bf16_t* xb = ws;                            // 16.78M  (attn out aliases this)
  bf16_t* qkv2 = ws + 16777216;               // 8192x2560 = 20.97M (q,k only)
  bf16_t* VT = qkv2 + 20971520;               // 2048x2048 = 4.19M (V transposed)
  bf16_t* WqkvT = VT + 4194304;               // 3072x2048 = 6.29M
  bf16_t* WpT = WqkvT + 6291456;              // 2048x2048 = 4.19M
  float2* tab = (float2*)(WpT + 4194304);     // 1MB table after WpT

  k_prep<<<dim3(296, 64), 256, 0, stream>>>(x, Wq, Wk, Wv, Wp, xb, WqkvT, WpT, tab);

  k_gemm_bt<true><<<384, 512, 0, stream>>>(xb, WqkvT, qkv2, VT, nullptr, nullptr, tab, 8192, 3072, 2048, 384);
  k_attn<<<1024, 256, 0, stream>>>(qkv2, VT, xb);
  k_gemm_bt<false><<<256, 512, 0, stream>>>(xb, WpT, nullptr, nullptr, out, bp, nullptr, 8192, 2048, 2048, 256);
}